// Round 10
// baseline (213.288 us; speedup 1.0000x reference)
//
#include <hip/hip_runtime.h>

// ---------------------------------------------------------------------------
// Causal MHSA. B=2, T=2048, D=1024, H=16, hd=64. fp32 in -> bf16 internal ->
// fp32 out. R10: attention rebuilt barrier-free: single-wave blocks, K/V
// fragments loaded directly global->register (coalesced 128B lines), P
// round-trip through wave-private LDS, no __syncthreads anywhere. 2 q-frags
// per wave share K/V regs (halves L2 traffic). GEMMs reverted to BK=32
// (BK=64's 128B row stride caused 16-way read conflicts, 9.4e6 in R9).
// ---------------------------------------------------------------------------

#define T_SEQ 2048
#define D_MODEL 1024
#define NEG_BIG (-1.0e30f)
#define Q_SCALE 0.18033688f   // 0.125 * log2(e): attention uses exp2 directly

typedef float f32x4 __attribute__((ext_vector_type(4)));
typedef short s16x8 __attribute__((ext_vector_type(8)));
typedef __bf16 bf16x8 __attribute__((ext_vector_type(8)));

__device__ __forceinline__ f32x4 mfma16(s16x8 a, s16x8 b, f32x4 c) {
    // C[m][n]=sum_k A[m][k]B[n][k]; lane: a=A[m=l16][k=quad*8+j],
    // b=B[n=l16][k=quad*8+j]; C: col(l16)=n, row(quad*4+r)=m
    return __builtin_amdgcn_mfma_f32_16x16x32_bf16(
        __builtin_bit_cast(bf16x8, a), __builtin_bit_cast(bf16x8, b), c, 0, 0, 0);
}

__device__ __forceinline__ short f2bf(float f) {          // RNE
    unsigned int u = __float_as_uint(f);
    u += 0x7fffu + ((u >> 16) & 1u);
    return (short)(u >> 16);
}
__device__ __forceinline__ unsigned f2bfu(float f) {
    unsigned int u = __float_as_uint(f);
    u += 0x7fffu + ((u >> 16) & 1u);
    return u >> 16;
}
__device__ __forceinline__ unsigned f2bfu_fast(float f) { // RN-away, positive
    return (__float_as_uint(f) + 0x8000u) >> 16;
}
__device__ __forceinline__ float bf2f(short s) {
    return __uint_as_float(((unsigned int)(unsigned short)s) << 16);
}

__device__ __forceinline__ void async_lds16(const short* g, short* l) {
    __builtin_amdgcn_global_load_lds(
        (const __attribute__((address_space(1))) unsigned int*)g,
        (__attribute__((address_space(3))) unsigned int*)l, 16, 0, 0);
}

// ---------------------------------------------------------------------------
// Fused canon: five fp32 inputs -> bf16, float4-vectorized, one launch.
// ---------------------------------------------------------------------------
#define N_X   4194304
#define N_WI  3145728
#define N_BI  3072
#define N_WO  1048576
#define N_BO  1024
#define V_X   (N_X  / 4)
#define V_WI  (N_WI / 4)
#define V_BI  (N_BI / 4)
#define V_WO  (N_WO / 4)
#define V_BO  (N_BO / 4)
#define V_TOT (V_X + V_WI + V_BI + V_WO + V_BO)

__global__ __launch_bounds__(256) void canon_all_kernel(
    const float* __restrict__ x, const float* __restrict__ wi,
    const float* __restrict__ bi, const float* __restrict__ wo,
    const float* __restrict__ bo,
    short* __restrict__ xb, short* __restrict__ wib, short* __restrict__ bib,
    short* __restrict__ wob, short* __restrict__ bob)
{
    int i = blockIdx.x * 256 + threadIdx.x;
    if (i >= V_TOT) return;
    const float* src; short* dst; int off;
    if      (i < V_X)                    { src = x;  dst = xb;  off = i; }
    else if (i < V_X+V_WI)               { src = wi; dst = wib; off = i - V_X; }
    else if (i < V_X+V_WI+V_BI)          { src = bi; dst = bib; off = i - V_X - V_WI; }
    else if (i < V_X+V_WI+V_BI+V_WO)     { src = wo; dst = wob; off = i - V_X - V_WI - V_BI; }
    else                                 { src = bo; dst = bob; off = i - V_X - V_WI - V_BI - V_WO; }
    float4 v = ((const float4*)src)[off];
    short4 o = { f2bf(v.x), f2bf(v.y), f2bf(v.z), f2bf(v.w) };
    ((short4*)dst)[off] = o;
}

// ---------------------------------------------------------------------------
// GEMM1 (m97 structure, BK=32): qkv = x @ w_in^T + b_in.
// q(xQ_SCALE)/k/v -> [B,H,T,64].
// ---------------------------------------------------------------------------
__global__ __launch_bounds__(256) void gemm_qkv_kernel(
    const short* __restrict__ A, const short* __restrict__ B,
    const short* __restrict__ bias,
    short* __restrict__ qo, short* __restrict__ ko, short* __restrict__ vo)
{
    const int K = 1024;
    alignas(16) __shared__ short As[128][32];
    alignas(16) __shared__ short Bs[128][32];
    const int m0 = blockIdx.x * 128;
    const int n0 = blockIdx.y * 128;
    const int tid = threadIdx.x;
    const int lane = tid & 63;
    const int w = tid >> 6;
    const int wm = (w >> 1) * 64, wn = (w & 1) * 64;
    const int quad = lane >> 4, l16 = lane & 15;

    f32x4 acc[4][4];
    const f32x4 zero = {0.f, 0.f, 0.f, 0.f};
#pragma unroll
    for (int i = 0; i < 4; ++i)
#pragma unroll
        for (int j = 0; j < 4; ++j) acc[i][j] = zero;

    const int lrow = lane >> 2;
    const int lcol = (lane & 3) * 8;
    const short* gA0 = &A[(m0 + w*32      + lrow) * K + lcol];
    const short* gA1 = &A[(m0 + w*32 + 16 + lrow) * K + lcol];
    const short* gB0 = &B[(n0 + w*32      + lrow) * K + lcol];
    const short* gB1 = &B[(n0 + w*32 + 16 + lrow) * K + lcol];
    short* lA0 = &As[w*32][0];
    short* lA1 = &As[w*32 + 16][0];
    short* lB0 = &Bs[w*32][0];
    short* lB1 = &Bs[w*32 + 16][0];

    for (int k0 = 0; k0 < K; k0 += 32) {
        __syncthreads();
        async_lds16(gA0 + k0, lA0);
        async_lds16(gA1 + k0, lA1);
        async_lds16(gB0 + k0, lB0);
        async_lds16(gB1 + k0, lB1);
        __syncthreads();

        s16x8 af[4], bfr[4];
#pragma unroll
        for (int i = 0; i < 4; ++i) af[i]  = *(const s16x8*)&As[wm + i*16 + l16][quad*8];
#pragma unroll
        for (int j = 0; j < 4; ++j) bfr[j] = *(const s16x8*)&Bs[wn + j*16 + l16][quad*8];
#pragma unroll
        for (int i = 0; i < 4; ++i)
#pragma unroll
            for (int j = 0; j < 4; ++j)
                acc[i][j] = mfma16(af[i], bfr[j], acc[i][j]);
    }

#pragma unroll
    for (int j = 0; j < 4; ++j) {
        int n = n0 + wn + j*16 + l16;
        float bi = bf2f(bias[n]);
        int which = n >> 10;
        short* dst = (which == 0) ? qo : (which == 1) ? ko : vo;
        float scl = (which == 0) ? Q_SCALE : 1.0f;
        int h = (n >> 6) & 15, d = n & 63;
#pragma unroll
        for (int i = 0; i < 4; ++i) {
#pragma unroll
            for (int r = 0; r < 4; ++r) {
                int m = m0 + wm + i*16 + quad*4 + r;
                int b = m >> 11, t = m & 2047;
                float v = (acc[i][j][r] + bi) * scl;
                dst[(((b*16 + h) * 2048) + t) * 64 + d] = f2bf(v);
            }
        }
    }
}

// ---------------------------------------------------------------------------
// V transpose: [B,H,T,64] -> [B,H,64,T]. Coalesced float4 both sides.
// ---------------------------------------------------------------------------
__global__ __launch_bounds__(256) void transpose_v_kernel(
    const short* __restrict__ V, short* __restrict__ Vt)
{
    alignas(16) __shared__ short buf[64][72];
    const int bh = blockIdx.x;
    const int t0 = blockIdx.y * 64;
    const int tid = threadIdx.x;
    const int r = tid >> 2;
    const int c = (tid & 3) * 16;

    const short* src = V + ((size_t)bh * T_SEQ + t0) * 64;
    *(float4*)&buf[r][c]     = *(const float4*)&src[r * 64 + c];
    *(float4*)&buf[r][c + 8] = *(const float4*)&src[r * 64 + c + 8];
    __syncthreads();

    s16x8 o0, o1;
#pragma unroll
    for (int k2 = 0; k2 < 8; ++k2) {
        o0[k2] = buf[c + k2][r];
        o1[k2] = buf[c + 8 + k2][r];
    }
    short* dst = Vt + ((size_t)bh * 64 + r) * T_SEQ + t0;
    *(s16x8*)&dst[c]     = o0;
    *(s16x8*)&dst[c + 8] = o1;
}

// ---------------------------------------------------------------------------
// Flash attention v5 — barrier-free. One wave per block; wave owns 32 q rows
// (2 q-frags). K/V fragments loaded DIRECTLY global->register:
//   ka: K[(s0+sub*16+l16)*64 + quad*8]  -> 16 rows x full 128B lines
//   va: Vt[(dt*16+l16)*2048 + s0+quad*8] -> 16 rows, 64B+64B (va0+va1)
// S^T/O^T orientation; P via wave-private LDS (no barrier); exp2-domain
// no-max softmax. Zero __syncthreads. LPT + bh->XCD pinning via block order.
// ---------------------------------------------------------------------------
__global__ __launch_bounds__(64, 4) void attn_kernel(
    const short* __restrict__ Q, const short* __restrict__ K,
    const short* __restrict__ Vt, short* __restrict__ ctx)
{
    alignas(16) __shared__ short Pl[32][72];      // wave-private P [q][s]

    const int bid = blockIdx.x;                   // 2048 blocks
    const int bh = bid & 31;                      // bh%8 -> fixed XCD
    const int qf = 63 - (bid >> 5);               // heavy q-groups first (LPT)
    const int qr0 = qf * 32;                      // first q row of this wave
    const int lane = threadIdx.x;
    const int quad = lane >> 4, l16 = lane & 15;
    const int b = bh >> 4, h = bh & 15;

    const short* Qb  = Q  + bh * T_SEQ * 64;
    const short* Kb  = K  + bh * T_SEQ * 64;
    const short* Vbt = Vt + (size_t)bh * 64 * T_SEQ;

    s16x8 qa0[2], qa1[2];
#pragma unroll
    for (int qs = 0; qs < 2; ++qs) {
        const short* qrow = Qb + (qr0 + qs*16 + l16) * 64;
        qa0[qs] = *(const s16x8*)(qrow + quad*8);
        qa1[qs] = *(const s16x8*)(qrow + 32 + quad*8);
    }

    const f32x4 zero = {0.f, 0.f, 0.f, 0.f};
    f32x4 o[2][4];
#pragma unroll
    for (int qs = 0; qs < 2; ++qs)
#pragma unroll
        for (int dt = 0; dt < 4; ++dt) o[qs][dt] = zero;
    float lsum[2] = {0.f, 0.f};

    const int s_max = (qr0 >> 6) << 6;            // diagonal tile base

    for (int s0 = 0; s0 <= s_max; s0 += 64) {
        // K frags: global -> regs (coalesced lines), shared by both q-frags
        s16x8 ka0[4], ka1[4];
#pragma unroll
        for (int sub = 0; sub < 4; ++sub) {
            const short* kr = &Kb[(s0 + sub*16 + l16) * 64 + quad*8];
            ka0[sub] = *(const s16x8*)kr;
            ka1[sub] = *(const s16x8*)(kr + 32);
        }

        // S^T -> exp2 -> Pl (packed b64 writes)
#pragma unroll
        for (int qs = 0; qs < 2; ++qs) {
            const int qg = qr0 + qs*16 + l16;
#pragma unroll
            for (int sub = 0; sub < 4; ++sub) {
                f32x4 S = mfma16(ka1[sub], qa1[qs], mfma16(ka0[sub], qa0[qs], zero));
                if (s0 == s_max) {                // diagonal: causal mask
                    int sb = s0 + sub*16 + quad*4;
#pragma unroll
                    for (int r = 0; r < 4; ++r)
                        if (sb + r > qg) S[r] = NEG_BIG;
                }
                float p0 = exp2f(S[0]), p1 = exp2f(S[1]);
                float p2 = exp2f(S[2]), p3 = exp2f(S[3]);
                lsum[qs] += (p0 + p1) + (p2 + p3);
                uint2 pk;
                pk.x = f2bfu_fast(p0) | (f2bfu_fast(p1) << 16);
                pk.y = f2bfu_fast(p2) | (f2bfu_fast(p3) << 16);
                *(uint2*)&Pl[qs*16 + l16][sub*16 + quad*4] = pk;
            }
        }
        // wave-private LDS: in-order within wave, no barrier

        // V frags: global -> regs, shared by both q-frags
        s16x8 va0[4], va1[4];
#pragma unroll
        for (int dt = 0; dt < 4; ++dt) {
            const short* vr = &Vbt[(size_t)(dt*16 + l16) * T_SEQ + s0 + quad*8];
            va0[dt] = *(const s16x8*)vr;
            va1[dt] = *(const s16x8*)(vr + 32);
        }

        // O^T += V^T P^T
#pragma unroll
        for (int qs = 0; qs < 2; ++qs) {
            s16x8 pb0 = *(const s16x8*)&Pl[qs*16 + l16][quad*8];
            s16x8 pb1 = *(const s16x8*)&Pl[qs*16 + l16][32 + quad*8];
#pragma unroll
            for (int dt = 0; dt < 4; ++dt)
                o[qs][dt] = mfma16(va1[dt], pb1, mfma16(va0[dt], pb0, o[qs][dt]));
        }
    }

    // epilogue: reduce lsum over quads (same q lives in 4 quads), store O^T
#pragma unroll
    for (int qs = 0; qs < 2; ++qs) {
        float l = lsum[qs];
        l += __shfl_xor(l, 16, 64);
        l += __shfl_xor(l, 32, 64);
        float inv = 1.0f / l;
        int qg = qr0 + qs*16 + l16;
        int base = (b * T_SEQ + qg) * D_MODEL + h * 64;
#pragma unroll
        for (int dt = 0; dt < 4; ++dt) {
            uint2 pk;
            pk.x = f2bfu(o[qs][dt][0] * inv) | (f2bfu(o[qs][dt][1] * inv) << 16);
            pk.y = f2bfu(o[qs][dt][2] * inv) | (f2bfu(o[qs][dt][3] * inv) << 16);
            *(uint2*)&ctx[base + dt*16 + quad*4] = pk;
        }
    }
}

// ---------------------------------------------------------------------------
// GEMM2 (BK=32): out = ctx @ w_out^T + b_out, fp32 store. 128x64, 512 blocks.
// ---------------------------------------------------------------------------
__global__ __launch_bounds__(256) void gemm_out_kernel(
    const short* __restrict__ A, const short* __restrict__ B,
    const short* __restrict__ bias, float* __restrict__ out)
{
    const int K = 1024;
    alignas(16) __shared__ short As[128][32];
    alignas(16) __shared__ short Bs[64][32];
    const int m0 = blockIdx.x * 128;
    const int n0 = blockIdx.y * 64;
    const int tid = threadIdx.x;
    const int lane = tid & 63;
    const int w = tid >> 6;
    const int wm = (w >> 1) * 64, wn = (w & 1) * 32;
    const int quad = lane >> 4, l16 = lane & 15;

    f32x4 acc[4][2];
    const f32x4 zero = {0.f, 0.f, 0.f, 0.f};
#pragma unroll
    for (int i = 0; i < 4; ++i)
#pragma unroll
        for (int j = 0; j < 2; ++j) acc[i][j] = zero;

    const int lrow = lane >> 2;
    const int lcol = (lane & 3) * 8;
    const short* gA0 = &A[(m0 + w*32      + lrow) * K + lcol];
    const short* gA1 = &A[(m0 + w*32 + 16 + lrow) * K + lcol];
    const short* gB0 = &B[(n0 + w*16 + lrow) * K + lcol];
    short* lA0 = &As[w*32][0];
    short* lA1 = &As[w*32 + 16][0];
    short* lB0 = &Bs[w*16][0];

    for (int k0 = 0; k0 < K; k0 += 32) {
        __syncthreads();
        async_lds16(gA0 + k0, lA0);
        async_lds16(gA1 + k0, lA1);
        async_lds16(gB0 + k0, lB0);
        __syncthreads();

        s16x8 af[4], bfr[2];
#pragma unroll
        for (int i = 0; i < 4; ++i) af[i]  = *(const s16x8*)&As[wm + i*16 + l16][quad*8];
#pragma unroll
        for (int j = 0; j < 2; ++j) bfr[j] = *(const s16x8*)&Bs[wn + j*16 + l16][quad*8];
#pragma unroll
        for (int i = 0; i < 4; ++i)
#pragma unroll
            for (int j = 0; j < 2; ++j)
                acc[i][j] = mfma16(af[i], bfr[j], acc[i][j]);
    }

#pragma unroll
    for (int j = 0; j < 2; ++j) {
        int n = n0 + wn + j*16 + l16;
        float bi = bf2f(bias[n]);
#pragma unroll
        for (int i = 0; i < 4; ++i) {
#pragma unroll
            for (int r = 0; r < 4; ++r) {
                int m = m0 + wm + i*16 + quad*4 + r;
                out[m * 1024 + n] = acc[i][j][r] + bi;
            }
        }
    }
}

// ---------------------------------------------------------------------------
extern "C" void kernel_launch(void* const* d_in, const int* in_sizes, int n_in,
                              void* d_out, int out_size, void* d_ws, size_t ws_size,
                              hipStream_t stream) {
    float* out = (float*)d_out;
    char* ws = (char*)d_ws;

    const size_t MB = 1u << 20;
    short* xb     = (short*)(ws);            // 8 MB (reused as vtb later)
    short* w_inb  = (short*)(ws + 8*MB);     // 6 MB
    short* b_inb  = (short*)(ws + 14*MB);
    short* w_outb = (short*)(ws + 15*MB);    // 2 MB
    short* b_outb = (short*)(ws + 17*MB);
    short* qb     = (short*)(ws + 18*MB);    // 8 MB [B,H,T,64]
    short* kb     = (short*)(ws + 26*MB);    // 8 MB [B,H,T,64]
    short* vb     = (short*)(ws + 34*MB);    // 8 MB [B,H,T,64]
    short* ctxb   = (short*)(ws + 42*MB);    // 8 MB [B,T,D]
    short* vtb    = xb;                      // aliases xb (dead after gemm_qkv)

    canon_all_kernel<<<(V_TOT + 255) / 256, 256, 0, stream>>>(
        (const float*)d_in[0], (const float*)d_in[1], (const float*)d_in[2],
        (const float*)d_in[3], (const float*)d_in[4],
        xb, w_inb, b_inb, w_outb, b_outb);

    gemm_qkv_kernel<<<dim3(32, 24), 256, 0, stream>>>(xb, w_inb, b_inb, qb, kb, vb);
    transpose_v_kernel<<<dim3(32, 32), 256, 0, stream>>>(vb, vtb);
    attn_kernel<<<2048, 64, 0, stream>>>(qb, kb, vtb, ctxb);
    gemm_out_kernel<<<dim3(32, 16), 256, 0, stream>>>(ctxb, w_outb, b_outb, out);
}

// Round 11
// 181.944 us; speedup vs baseline: 1.1723x; 1.1723x over previous
//
#include <hip/hip_runtime.h>

// ---------------------------------------------------------------------------
// Causal MHSA. B=2, T=2048, D=1024, H=16, hd=64. fp32 in -> bf16 internal ->
// fp32 out. R11: best-measured assembly — R9's attention (4-wave blocks,
// 1024 blocks, K/V register prefetch; <=52.8us) + R10's BK=32 GEMMs
// (non-attn 132us) + fused canon + dedicated V-transpose.
// ---------------------------------------------------------------------------

#define T_SEQ 2048
#define D_MODEL 1024
#define NEG_BIG (-1.0e30f)
#define Q_SCALE 0.18033688f   // 0.125 * log2(e): attention uses exp2 directly

typedef float f32x4 __attribute__((ext_vector_type(4)));
typedef short s16x8 __attribute__((ext_vector_type(8)));
typedef __bf16 bf16x8 __attribute__((ext_vector_type(8)));

__device__ __forceinline__ f32x4 mfma16(s16x8 a, s16x8 b, f32x4 c) {
    // C[m][n]=sum_k A[m][k]B[n][k]; lane: a=A[m=l16][k=quad*8+j],
    // b=B[n=l16][k=quad*8+j]; C: col(l16)=n, row(quad*4+r)=m
    return __builtin_amdgcn_mfma_f32_16x16x32_bf16(
        __builtin_bit_cast(bf16x8, a), __builtin_bit_cast(bf16x8, b), c, 0, 0, 0);
}

__device__ __forceinline__ short f2bf(float f) {          // RNE
    unsigned int u = __float_as_uint(f);
    u += 0x7fffu + ((u >> 16) & 1u);
    return (short)(u >> 16);
}
__device__ __forceinline__ unsigned f2bfu(float f) {
    unsigned int u = __float_as_uint(f);
    u += 0x7fffu + ((u >> 16) & 1u);
    return u >> 16;
}
__device__ __forceinline__ unsigned f2bfu_fast(float f) { // RN-away, positive
    return (__float_as_uint(f) + 0x8000u) >> 16;
}
__device__ __forceinline__ float bf2f(short s) {
    return __uint_as_float(((unsigned int)(unsigned short)s) << 16);
}

__device__ __forceinline__ void async_lds16(const short* g, short* l) {
    __builtin_amdgcn_global_load_lds(
        (const __attribute__((address_space(1))) unsigned int*)g,
        (__attribute__((address_space(3))) unsigned int*)l, 16, 0, 0);
}

// ---------------------------------------------------------------------------
// Fused canon: five fp32 inputs -> bf16, float4-vectorized, one launch.
// ---------------------------------------------------------------------------
#define N_X   4194304
#define N_WI  3145728
#define N_BI  3072
#define N_WO  1048576
#define N_BO  1024
#define V_X   (N_X  / 4)
#define V_WI  (N_WI / 4)
#define V_BI  (N_BI / 4)
#define V_WO  (N_WO / 4)
#define V_BO  (N_BO / 4)
#define V_TOT (V_X + V_WI + V_BI + V_WO + V_BO)

__global__ __launch_bounds__(256) void canon_all_kernel(
    const float* __restrict__ x, const float* __restrict__ wi,
    const float* __restrict__ bi, const float* __restrict__ wo,
    const float* __restrict__ bo,
    short* __restrict__ xb, short* __restrict__ wib, short* __restrict__ bib,
    short* __restrict__ wob, short* __restrict__ bob)
{
    int i = blockIdx.x * 256 + threadIdx.x;
    if (i >= V_TOT) return;
    const float* src; short* dst; int off;
    if      (i < V_X)                    { src = x;  dst = xb;  off = i; }
    else if (i < V_X+V_WI)               { src = wi; dst = wib; off = i - V_X; }
    else if (i < V_X+V_WI+V_BI)          { src = bi; dst = bib; off = i - V_X - V_WI; }
    else if (i < V_X+V_WI+V_BI+V_WO)     { src = wo; dst = wob; off = i - V_X - V_WI - V_BI; }
    else                                 { src = bo; dst = bob; off = i - V_X - V_WI - V_BI - V_WO; }
    float4 v = ((const float4*)src)[off];
    short4 o = { f2bf(v.x), f2bf(v.y), f2bf(v.z), f2bf(v.w) };
    ((short4*)dst)[off] = o;
}

// ---------------------------------------------------------------------------
// GEMM1 (m97 structure, BK=32): qkv = x @ w_in^T + b_in.
// q(xQ_SCALE)/k/v -> [B,H,T,64].
// ---------------------------------------------------------------------------
__global__ __launch_bounds__(256) void gemm_qkv_kernel(
    const short* __restrict__ A, const short* __restrict__ B,
    const short* __restrict__ bias,
    short* __restrict__ qo, short* __restrict__ ko, short* __restrict__ vo)
{
    const int K = 1024;
    alignas(16) __shared__ short As[128][32];
    alignas(16) __shared__ short Bs[128][32];
    const int m0 = blockIdx.x * 128;
    const int n0 = blockIdx.y * 128;
    const int tid = threadIdx.x;
    const int lane = tid & 63;
    const int w = tid >> 6;
    const int wm = (w >> 1) * 64, wn = (w & 1) * 64;
    const int quad = lane >> 4, l16 = lane & 15;

    f32x4 acc[4][4];
    const f32x4 zero = {0.f, 0.f, 0.f, 0.f};
#pragma unroll
    for (int i = 0; i < 4; ++i)
#pragma unroll
        for (int j = 0; j < 4; ++j) acc[i][j] = zero;

    const int lrow = lane >> 2;
    const int lcol = (lane & 3) * 8;
    const short* gA0 = &A[(m0 + w*32      + lrow) * K + lcol];
    const short* gA1 = &A[(m0 + w*32 + 16 + lrow) * K + lcol];
    const short* gB0 = &B[(n0 + w*32      + lrow) * K + lcol];
    const short* gB1 = &B[(n0 + w*32 + 16 + lrow) * K + lcol];
    short* lA0 = &As[w*32][0];
    short* lA1 = &As[w*32 + 16][0];
    short* lB0 = &Bs[w*32][0];
    short* lB1 = &Bs[w*32 + 16][0];

    for (int k0 = 0; k0 < K; k0 += 32) {
        __syncthreads();
        async_lds16(gA0 + k0, lA0);
        async_lds16(gA1 + k0, lA1);
        async_lds16(gB0 + k0, lB0);
        async_lds16(gB1 + k0, lB1);
        __syncthreads();

        s16x8 af[4], bfr[4];
#pragma unroll
        for (int i = 0; i < 4; ++i) af[i]  = *(const s16x8*)&As[wm + i*16 + l16][quad*8];
#pragma unroll
        for (int j = 0; j < 4; ++j) bfr[j] = *(const s16x8*)&Bs[wn + j*16 + l16][quad*8];
#pragma unroll
        for (int i = 0; i < 4; ++i)
#pragma unroll
            for (int j = 0; j < 4; ++j)
                acc[i][j] = mfma16(af[i], bfr[j], acc[i][j]);
    }

#pragma unroll
    for (int j = 0; j < 4; ++j) {
        int n = n0 + wn + j*16 + l16;
        float bi = bf2f(bias[n]);
        int which = n >> 10;
        short* dst = (which == 0) ? qo : (which == 1) ? ko : vo;
        float scl = (which == 0) ? Q_SCALE : 1.0f;
        int h = (n >> 6) & 15, d = n & 63;
#pragma unroll
        for (int i = 0; i < 4; ++i) {
#pragma unroll
            for (int r = 0; r < 4; ++r) {
                int m = m0 + wm + i*16 + quad*4 + r;
                int b = m >> 11, t = m & 2047;
                float v = (acc[i][j][r] + bi) * scl;
                dst[(((b*16 + h) * 2048) + t) * 64 + d] = f2bf(v);
            }
        }
    }
}

// ---------------------------------------------------------------------------
// V transpose: [B,H,T,64] -> [B,H,64,T]. Coalesced float4 both sides.
// ---------------------------------------------------------------------------
__global__ __launch_bounds__(256) void transpose_v_kernel(
    const short* __restrict__ V, short* __restrict__ Vt)
{
    alignas(16) __shared__ short buf[64][72];
    const int bh = blockIdx.x;
    const int t0 = blockIdx.y * 64;
    const int tid = threadIdx.x;
    const int r = tid >> 2;
    const int c = (tid & 3) * 16;

    const short* src = V + ((size_t)bh * T_SEQ + t0) * 64;
    *(float4*)&buf[r][c]     = *(const float4*)&src[r * 64 + c];
    *(float4*)&buf[r][c + 8] = *(const float4*)&src[r * 64 + c + 8];
    __syncthreads();

    s16x8 o0, o1;
#pragma unroll
    for (int k2 = 0; k2 < 8; ++k2) {
        o0[k2] = buf[c + k2][r];
        o1[k2] = buf[c + 8 + k2][r];
    }
    short* dst = Vt + ((size_t)bh * 64 + r) * T_SEQ + t0;
    *(s16x8*)&dst[c]     = o0;
    *(s16x8*)&dst[c + 8] = o1;
}

// ---------------------------------------------------------------------------
// Flash attention (R9 version — best measured): q-tile 64 per block, 1024
// blocks (4/CU), 4 waves; S^T/O^T orientation; exp2-domain no-max softmax;
// all-wide LDS writes; register prefetch of next K/V tile across compute.
// ---------------------------------------------------------------------------
__global__ __launch_bounds__(256) void attn_kernel(
    const short* __restrict__ Q, const short* __restrict__ K,
    const short* __restrict__ Vt, short* __restrict__ ctx)
{
    alignas(16) __shared__ short Ks[64][72];      // [s][d]
    alignas(16) __shared__ short Vs[64][72];      // [d][s]
    alignas(16) __shared__ short Pl[4][16][72];   // per-wave [q][s]

    const int bh = blockIdx.x;
    const int qt = 31 - (int)blockIdx.y;          // heavy tiles first (LPT)
    const int qbase = qt * 64;
    const int tid = threadIdx.x;
    const int w = tid >> 6, lane = tid & 63;
    const int quad = lane >> 4, l16 = lane & 15;
    const int b = bh >> 4, h = bh & 15;

    const short* Qb  = Q  + bh * T_SEQ * 64;
    const short* Kb  = K  + bh * T_SEQ * 64;
    const short* Vbt = Vt + (size_t)bh * 64 * T_SEQ;

    const short* qrow = Qb + (qbase + w*16 + l16) * 64;
    const s16x8 qa0 = *(const s16x8*)(qrow + quad*8);
    const s16x8 qa1 = *(const s16x8*)(qrow + 32 + quad*8);

    const f32x4 zero = {0.f, 0.f, 0.f, 0.f};
    f32x4 o[4];
#pragma unroll
    for (int dt = 0; dt < 4; ++dt) o[dt] = zero;
    float lsum = 0.f;

    const int sr  = tid >> 3;                     // 0..31
    const int scl = (tid & 7) * 8;                // 0..56
    const int qg  = qbase + w*16 + l16;

    // preload tile s0=0
    float4 kf0 = *(const float4*)&Kb[sr * 64 + scl];
    float4 kf1 = *(const float4*)&Kb[(sr + 32) * 64 + scl];
    float4 vf0 = *(const float4*)&Vbt[(size_t)sr * T_SEQ + scl];
    float4 vf1 = *(const float4*)&Vbt[(size_t)(sr + 32) * T_SEQ + scl];

    for (int s0 = 0; s0 <= qbase; s0 += 64) {
        __syncthreads();
        *(float4*)&Ks[sr][scl]    = kf0;
        *(float4*)&Ks[sr+32][scl] = kf1;
        *(float4*)&Vs[sr][scl]    = vf0;
        *(float4*)&Vs[sr+32][scl] = vf1;
        __syncthreads();

        if (s0 + 64 <= qbase) {                   // prefetch next tile
            kf0 = *(const float4*)&Kb[(s0 + 64 + sr) * 64 + scl];
            kf1 = *(const float4*)&Kb[(s0 + 64 + sr + 32) * 64 + scl];
            vf0 = *(const float4*)&Vbt[(size_t)sr * T_SEQ + s0 + 64 + scl];
            vf1 = *(const float4*)&Vbt[(size_t)(sr + 32) * T_SEQ + s0 + 64 + scl];
        }

        // S^T = K Q^T
#pragma unroll
        for (int sub = 0; sub < 4; ++sub) {
            s16x8 ka0 = *(const s16x8*)&Ks[sub*16 + l16][quad*8];
            s16x8 ka1 = *(const s16x8*)&Ks[sub*16 + l16][32 + quad*8];
            f32x4 S = mfma16(ka1, qa1, mfma16(ka0, qa0, zero));
            if (s0 == qbase) {                    // diagonal: causal mask
                int sb = s0 + sub*16 + quad*4;
#pragma unroll
                for (int r = 0; r < 4; ++r)
                    if (sb + r > qg) S[r] = NEG_BIG;
            }
            float p0 = exp2f(S[0]), p1 = exp2f(S[1]);
            float p2 = exp2f(S[2]), p3 = exp2f(S[3]);
            lsum += (p0 + p1) + (p2 + p3);
            uint2 pk;
            pk.x = f2bfu_fast(p0) | (f2bfu_fast(p1) << 16);
            pk.y = f2bfu_fast(p2) | (f2bfu_fast(p3) << 16);
            *(uint2*)&Pl[w][l16][sub*16 + quad*4] = pk;
        }
        // wave-private Pl: in-order within wave, no barrier

        // O^T += V^T P^T
        s16x8 pb0 = *(const s16x8*)&Pl[w][l16][quad*8];
        s16x8 pb1 = *(const s16x8*)&Pl[w][l16][32 + quad*8];
#pragma unroll
        for (int dt = 0; dt < 4; ++dt) {
            s16x8 va0 = *(const s16x8*)&Vs[dt*16 + l16][quad*8];
            s16x8 va1 = *(const s16x8*)&Vs[dt*16 + l16][32 + quad*8];
            o[dt] = mfma16(va1, pb1, mfma16(va0, pb0, o[dt]));
        }
    }

    lsum += __shfl_xor(lsum, 16, 64);
    lsum += __shfl_xor(lsum, 32, 64);
    float inv = 1.0f / lsum;
    int base = (b * T_SEQ + qg) * D_MODEL + h * 64;
#pragma unroll
    for (int dt = 0; dt < 4; ++dt) {
        uint2 pk;
        pk.x = f2bfu(o[dt][0] * inv) | (f2bfu(o[dt][1] * inv) << 16);
        pk.y = f2bfu(o[dt][2] * inv) | (f2bfu(o[dt][3] * inv) << 16);
        *(uint2*)&ctx[base + dt*16 + quad*4] = pk;
    }
}

// ---------------------------------------------------------------------------
// GEMM2 (BK=32): out = ctx @ w_out^T + b_out, fp32 store. 128x64, 512 blocks.
// ---------------------------------------------------------------------------
__global__ __launch_bounds__(256) void gemm_out_kernel(
    const short* __restrict__ A, const short* __restrict__ B,
    const short* __restrict__ bias, float* __restrict__ out)
{
    const int K = 1024;
    alignas(16) __shared__ short As[128][32];
    alignas(16) __shared__ short Bs[64][32];
    const int m0 = blockIdx.x * 128;
    const int n0 = blockIdx.y * 64;
    const int tid = threadIdx.x;
    const int lane = tid & 63;
    const int w = tid >> 6;
    const int wm = (w >> 1) * 64, wn = (w & 1) * 32;
    const int quad = lane >> 4, l16 = lane & 15;

    f32x4 acc[4][2];
    const f32x4 zero = {0.f, 0.f, 0.f, 0.f};
#pragma unroll
    for (int i = 0; i < 4; ++i)
#pragma unroll
        for (int j = 0; j < 2; ++j) acc[i][j] = zero;

    const int lrow = lane >> 2;
    const int lcol = (lane & 3) * 8;
    const short* gA0 = &A[(m0 + w*32      + lrow) * K + lcol];
    const short* gA1 = &A[(m0 + w*32 + 16 + lrow) * K + lcol];
    const short* gB0 = &B[(n0 + w*16 + lrow) * K + lcol];
    short* lA0 = &As[w*32][0];
    short* lA1 = &As[w*32 + 16][0];
    short* lB0 = &Bs[w*16][0];

    for (int k0 = 0; k0 < K; k0 += 32) {
        __syncthreads();
        async_lds16(gA0 + k0, lA0);
        async_lds16(gA1 + k0, lA1);
        async_lds16(gB0 + k0, lB0);
        __syncthreads();

        s16x8 af[4], bfr[2];
#pragma unroll
        for (int i = 0; i < 4; ++i) af[i]  = *(const s16x8*)&As[wm + i*16 + l16][quad*8];
#pragma unroll
        for (int j = 0; j < 2; ++j) bfr[j] = *(const s16x8*)&Bs[wn + j*16 + l16][quad*8];
#pragma unroll
        for (int i = 0; i < 4; ++i)
#pragma unroll
            for (int j = 0; j < 2; ++j)
                acc[i][j] = mfma16(af[i], bfr[j], acc[i][j]);
    }

#pragma unroll
    for (int j = 0; j < 2; ++j) {
        int n = n0 + wn + j*16 + l16;
        float bi = bf2f(bias[n]);
#pragma unroll
        for (int i = 0; i < 4; ++i) {
#pragma unroll
            for (int r = 0; r < 4; ++r) {
                int m = m0 + wm + i*16 + quad*4 + r;
                out[m * 1024 + n] = acc[i][j][r] + bi;
            }
        }
    }
}

// ---------------------------------------------------------------------------
extern "C" void kernel_launch(void* const* d_in, const int* in_sizes, int n_in,
                              void* d_out, int out_size, void* d_ws, size_t ws_size,
                              hipStream_t stream) {
    float* out = (float*)d_out;
    char* ws = (char*)d_ws;

    const size_t MB = 1u << 20;
    short* xb     = (short*)(ws);            // 8 MB (reused as vtb later)
    short* w_inb  = (short*)(ws + 8*MB);     // 6 MB
    short* b_inb  = (short*)(ws + 14*MB);
    short* w_outb = (short*)(ws + 15*MB);    // 2 MB
    short* b_outb = (short*)(ws + 17*MB);
    short* qb     = (short*)(ws + 18*MB);    // 8 MB [B,H,T,64]
    short* kb     = (short*)(ws + 26*MB);    // 8 MB [B,H,T,64]
    short* vb     = (short*)(ws + 34*MB);    // 8 MB [B,H,T,64]
    short* ctxb   = (short*)(ws + 42*MB);    // 8 MB [B,T,D]
    short* vtb    = xb;                      // aliases xb (dead after gemm_qkv)

    canon_all_kernel<<<(V_TOT + 255) / 256, 256, 0, stream>>>(
        (const float*)d_in[0], (const float*)d_in[1], (const float*)d_in[2],
        (const float*)d_in[3], (const float*)d_in[4],
        xb, w_inb, b_inb, w_outb, b_outb);

    gemm_qkv_kernel<<<dim3(32, 24), 256, 0, stream>>>(xb, w_inb, b_inb, qb, kb, vb);
    transpose_v_kernel<<<dim3(32, 32), 256, 0, stream>>>(vb, vtb);
    attn_kernel<<<dim3(32, 32), 256, 0, stream>>>(qb, kb, vtb, ctxb);
    gemm_out_kernel<<<dim3(32, 16), 256, 0, stream>>>(ctxb, w_outb, b_outb, out);
}